// Round 5
// baseline (4186.258 us; speedup 1.0000x reference)
//
#include <hip/hip_runtime.h>

// VaeRNNDecoder: 512-step LSTM with output feedback, B=256, H=512.
// Folded recurrence: gates_t = h_t @ W_eff^T + b_eff,  W_eff = W_ih@W_last + W_hh.
// ROUND 5: two-phase batch pipelining. 8 groups x 16 pair-blocks (160 rows).
// Each group's 32 batches split into halves A(0-15)/B(16-31) — independent
// recurrences sharing the register-resident weights. Ticks alternate A,B;
// during half X's tick we poll the OTHER half's counter (incremented a full
// tick ago) and prefetch its h into registers -> the LLC detect+load chain
// (~2000cy) is hidden under compute. Exchange protocol per half = the
// baseline-proven one: sc0sc1 stores, per-thread vmcnt(0) drain, LDS arrive
// counter (not __syncthreads: avoids draining in-flight prefetch), tid0
// global counter add, bounded polls.
// NOTE (r1/r2): sc0-only XCD-local exchange is BROKEN — do not reintroduce.
// NOTE (r3): polling must stay narrow (one line); wide polls flood the LLC.
// NOTE (r4): barrier RMW width is NOT a cost; broadcast BW and latency are.

#define HH 512
#define TT 512

typedef _Float16 half8 __attribute__((ext_vector_type(8)));
typedef float f32x4 __attribute__((ext_vector_type(4)));

__device__ __forceinline__ float sigm(float x) { return 1.0f / (1.0f + __expf(-x)); }
__device__ __forceinline__ float tanh_(float x) { return 1.0f - 2.0f / (__expf(2.0f * x) + 1.0f); }
__device__ __forceinline__ unsigned short f16b(float x) {
    _Float16 h = (_Float16)x;
    return __builtin_bit_cast(unsigned short, h);
}

// ---------------- K1: W_eff gate rows -> Wbig (packed, f16) ----------------
__global__ __launch_bounds__(256) void k_weff(const float* __restrict__ Wih,
                                              const float* __restrict__ Whh,
                                              const float* __restrict__ Wlast,
                                              unsigned short* __restrict__ Wbig) {
    __shared__ float wih[16 * 512];
    const int tid = threadIdx.x;
    const int r0 = blockIdx.x * 16;
    for (int i = tid; i < (16 * 512) / 4; i += 256) {
        ((float4*)wih)[i] = ((const float4*)(Wih + (size_t)r0 * 512))[i];
    }
    __syncthreads();
    float acc0[16], acc1[16];
#pragma unroll
    for (int rr = 0; rr < 16; ++rr) { acc0[rr] = 0.f; acc1[rr] = 0.f; }
    const int k0 = tid * 2;
    for (int j = 0; j < 512; ++j) {
        const float2 wl = *(const float2*)(Wlast + (size_t)j * 512 + k0);
#pragma unroll
        for (int rr = 0; rr < 16; ++rr) {
            const float a = wih[rr * 512 + j];
            acc0[rr] += a * wl.x;
            acc1[rr] += a * wl.y;
        }
    }
#pragma unroll
    for (int rr = 0; rr < 16; ++rr) {
        const int gr = r0 + rr;
        const int q = gr >> 9, j = gr & 511;
        const int dst = 80 * (j >> 4) + q * 16 + (j & 15);
        const float v0 = acc0[rr] + Whh[(size_t)gr * 512 + k0];
        const float v1 = acc1[rr] + Whh[(size_t)gr * 512 + k0 + 1];
        Wbig[(size_t)dst * 512 + k0] = f16b(v0);
        Wbig[(size_t)dst * 512 + k0 + 1] = f16b(v1);
    }
}

// ---------------- K2: pack W0big, y-rows, biases, hbuf init, counters ------
__global__ __launch_bounds__(256) void k_pack(const float* __restrict__ z,
                                              const float* __restrict__ Wih,
                                              const float* __restrict__ Whh,
                                              const float* __restrict__ bih,
                                              const float* __restrict__ bhh,
                                              const float* __restrict__ Wlast,
                                              const float* __restrict__ blast,
                                              unsigned short* __restrict__ Wbig,
                                              unsigned short* __restrict__ W0big,
                                              float* __restrict__ biasEff,
                                              float* __restrict__ bias0,
                                              unsigned short* __restrict__ hbuf,
                                              unsigned int* __restrict__ counters) {
    const int nthr = gridDim.x * blockDim.x;
    const int gtid = blockIdx.x * blockDim.x + threadIdx.x;
    for (int e = gtid; e < 2560 * 512; e += nthr) {
        const int r = e >> 9, k = e & 511;
        const int s = r / 80, rem = r - s * 80;
        const int tau = rem >> 4, jj = rem & 15;
        const int j = s * 16 + jj;
        if (tau == 4) {
            const unsigned short v = f16b(Wlast[(size_t)j * 512 + k]);
            Wbig[e] = v;
            W0big[e] = v;
        } else {
            const int gr = tau * 512 + j;
            W0big[e] = f16b(Wih[(size_t)gr * 512 + k] + Whh[(size_t)gr * 512 + k]);
        }
    }
    for (int r = gtid; r < 2560; r += nthr) {
        const int s = r / 80, rem = r - s * 80;
        const int tau = rem >> 4, jj = rem & 15;
        const int j = s * 16 + jj;
        if (tau == 4) {
            bias0[r] = blast[j];
            biasEff[r] = blast[j];
        } else {
            const int gr = tau * 512 + j;
            const float base = bih[gr] + bhh[gr];
            float dot = 0.f;
            for (int k = 0; k < 512; ++k) dot += Wih[(size_t)gr * 512 + k] * blast[k];
            bias0[r] = base;
            biasEff[r] = base + dot;
        }
    }
    // hbuf layout: [g][buf 0..3][16 batch][512], buf = half*2 + parity.
    // seed parity0 of each half with z.
    for (int e = gtid; e < 256 * 512; e += nthr) {
        const int bg = e >> 9, k = e & 511;
        const int g = bg >> 5, bl = bg & 31;
        const int hf = bl >> 4, b16 = bl & 15;
        hbuf[(size_t)g * 32768 + (size_t)(hf * 2) * 8192 + b16 * 512 + k] = f16b(z[e]);
    }
    for (int e = gtid; e < 512; e += nthr) counters[e] = 0u;
}

// ---------------- K3: persistent recurrence, 2-phase pipelined ----------------
// 128 blocks = 8 groups (blockIdx&7) x 16 pairs (blockIdx>>3). Pair-block owns
// slices {2p,2p+1} = 160 packed rows. 1026 ticks: tick t -> half=t&1, k=t>>1.
// Waves: w0: sliceA x {i,f,g}; w1: sliceA x {o,y}; w2: sliceB x {i,f,g};
//        w3: sliceB x {o,y}. One 16-row M-tile per tick (the half's batches).
__global__ __launch_bounds__(256, 1) void k_lstm(const unsigned short* __restrict__ Wbig,
                                                 const unsigned short* __restrict__ W0big,
                                                 const float* __restrict__ biasEff,
                                                 const float* __restrict__ bias0,
                                                 unsigned short* __restrict__ hbuf,
                                                 unsigned int* __restrict__ counters,
                                                 const float* __restrict__ z,
                                                 float* __restrict__ out) {
    const int g = blockIdx.x & 7;
    const int pair = blockIdx.x >> 3;
    const int tid = threadIdx.x;
    const int wave = tid >> 6;
    const int lane = tid & 63;
    const int l15 = lane & 15;
    const int q4 = lane >> 4;

    __shared__ unsigned short hstage[16 * 520];  // one half's h, padded rows
    __shared__ float gatesL[2 * 16 * 68];        // [sl][b][i f g o], stride 68
    __shared__ float cL[4 * 16 * 18];            // [half*2+sl][b][16], stride 18
    __shared__ unsigned int arrive;              // intra-block store-drain arrivals

    const int sl = wave >> 1;
    const int slice = 2 * pair + sl;
    const int ntile0 = (wave & 1) ? 3 : 0;
    const int ntcount = (wave & 1) ? 2 : 3;

    unsigned short* hbg = hbuf + (size_t)g * 32768;
    unsigned int* cntA = counters + g * 64;
    unsigned int* cntB = counters + g * 64 + 16;

    if (tid == 0) arrive = 0u;

    // c init from z (fp32 exact): both halves x both slices
    for (int idx = tid; idx < 1024; idx += 256) {
        const int jj = idx & 15, b = (idx >> 4) & 15;
        const int s2 = (idx >> 8) & 1, hf = idx >> 9;
        cL[((hf * 2 + s2) * 16 + b) * 18 + jj] =
            z[(size_t)(g * 32 + hf * 16 + b) * 512 + 16 * (2 * pair + s2) + jj];
    }

    // persistent B-fragments (fp16 weights), start with W0
    half8 bfrag[3][16];
#pragma unroll
    for (int tt = 0; tt < 3; ++tt) {
        if (tt < ntcount) {
            const int row = 80 * slice + (ntile0 + tt) * 16 + l15;
#pragma unroll
            for (int kk = 0; kk < 16; ++kk) {
                bfrag[tt][kk] = *(const half8*)(W0big + (size_t)row * 512 + kk * 32 + q4 * 8);
            }
        }
    }
    float bias0v[3], biasEv[3];
#pragma unroll
    for (int tt = 0; tt < 3; ++tt) {
        if (tt < ntcount) {
            const int r = 80 * slice + (ntile0 + tt) * 16 + l15;
            bias0v[tt] = bias0[r];
            biasEv[tt] = biasEff[r];
        } else {
            bias0v[tt] = 0.f;
            biasEv[tt] = 0.f;
        }
    }

    __syncthreads();  // cL + arrive init visible

    // prologue: prefetch hA(0) (buffer 0) into registers, no wait yet
    half8 st[4];
    {
        const char* p = (const char*)hbg + tid * 16;
        asm volatile(
            "global_load_dwordx4 %0, %4, off sc0 sc1\n\t"
            "global_load_dwordx4 %1, %5, off sc0 sc1\n\t"
            "global_load_dwordx4 %2, %6, off sc0 sc1\n\t"
            "global_load_dwordx4 %3, %7, off sc0 sc1"
            : "=&v"(st[0]), "=&v"(st[1]), "=&v"(st[2]), "=&v"(st[3])
            : "v"(p), "v"(p + 4096), "v"(p + 8192), "v"(p + 12288)
            : "memory");
    }

    for (int tick = 0; tick < 1026; ++tick) {
        const int k = tick >> 1;
        const int half = tick & 1;
        const bool last = (k == 512);

        // ---- (1) prefetched h -> LDS (vmcnt(0): loads landed; also drains strays)
        asm volatile("s_waitcnt vmcnt(0)" ::: "memory");
#pragma unroll
        for (int i = 0; i < 4; ++i) {
            const int ci = i * 256 + tid;  // 16B chunk 0..1023: 16 rows x 64 chunks
            const int row = ci >> 6, col = ci & 63;
            *(half8*)(hstage + row * 520 + col * 8) = st[i];
        }
        __syncthreads();

        // ---- (2) MFMA: one 16-batch M-tile x [gates | y] ----
        f32x4 acc[3];
#pragma unroll
        for (int tt = 0; tt < 3; ++tt) {
            const float bv = (k == 0) ? bias0v[tt] : biasEv[tt];
            acc[tt] = (f32x4){bv, bv, bv, bv};
        }
#pragma unroll
        for (int kk = 0; kk < 16; ++kk) {
            const half8 a = *(const half8*)(hstage + l15 * 520 + kk * 32 + q4 * 8);
#pragma unroll
            for (int tt = 0; tt < 3; ++tt) {
                if (tt < ntcount)
                    acc[tt] = __builtin_amdgcn_mfma_f32_16x16x32_f16(a, bfrag[tt][kk], acc[tt], 0, 0, 0);
            }
        }

        // ---- (3) gate tiles -> LDS (skip on last-k ticks) ----
        if (!last) {
            const int nst = (wave & 1) ? 1 : 3;
#pragma unroll
            for (int tt = 0; tt < 3; ++tt) {
                if (tt < nst) {
                    const int col = (ntile0 + tt) * 16 + l15;
#pragma unroll
                    for (int r = 0; r < 4; ++r) {
                        const int m = q4 * 4 + r;
                        gatesL[(sl * 16 + m) * 68 + col] = acc[tt][r];
                    }
                }
            }
        }
        __syncthreads();  // no VMEM in flight here (y stores come after)

        // ---- (4) y_{k-1} output (waves 1/3, acc[1]) ----
        if ((wave & 1) && k >= 1) {
            const int n = 16 * slice + l15;
#pragma unroll
            for (int r = 0; r < 4; ++r) {
                const int m = q4 * 4 + r;
                const size_t off =
                    (size_t)(g * 32 + half * 16 + m) * (TT * HH) + (size_t)(k - 1) * HH + n;
                out[off] = acc[1][r];
            }
        }

        if (!last) {
            // ---- (5) cell update: 2 cells/thread; publish h(k+1) ----
            const int b = tid >> 4, jp = tid & 15;
            const int j0 = jp * 2;
            const int s2 = j0 >> 4, jj = j0 & 15;
            const float* gb = gatesL + (s2 * 16 + b) * 68;
            const float2 iv = *(const float2*)(gb + jj);
            const float2 fvv = *(const float2*)(gb + 16 + jj);
            const float2 gv = *(const float2*)(gb + 32 + jj);
            const float2 ov = *(const float2*)(gb + 48 + jj);
            float* cp = cL + ((half * 2 + s2) * 16 + b) * 18 + jj;
            float2 cv = *(const float2*)cp;
            const float c0 = sigm(fvv.x) * cv.x + sigm(iv.x) * tanh_(gv.x);
            const float c1 = sigm(fvv.y) * cv.y + sigm(iv.y) * tanh_(gv.y);
            const float h0 = sigm(ov.x) * tanh_(c0);
            const float h1 = sigm(ov.y) * tanh_(c1);
            cv.x = c0;
            cv.y = c1;
            *(float2*)cp = cv;
            unsigned short* hd = hbg + (half * 2 + ((k + 1) & 1)) * 8192;
            const unsigned int packed = (unsigned int)f16b(h0) | ((unsigned int)f16b(h1) << 16);
            unsigned int* pp = (unsigned int*)(hd + b * 512 + 16 * (2 * pair + s2) + jj);
            asm volatile("global_store_dword %0, %1, off sc0 sc1" ::"v"(pp), "v"(packed)
                         : "memory");

            // after both halves' step 0 (end of tick 1): swap W0 -> W_eff
            if (tick == 1) {
#pragma unroll
                for (int tt = 0; tt < 3; ++tt) {
                    if (tt < ntcount) {
                        const int row = 80 * slice + (ntile0 + tt) * 16 + l15;
#pragma unroll
                        for (int kk = 0; kk < 16; ++kk) {
                            bfrag[tt][kk] =
                                *(const half8*)(Wbig + (size_t)row * 512 + kk * 32 + q4 * 8);
                        }
                    }
                }
            }

            // ---- (6) per-thread drain, LDS arrive, tid0 publishes counter ----
            asm volatile("s_waitcnt vmcnt(0)" ::: "memory");  // h (+y) stores at LLC
            if (lane == 0) atomicAdd(&arrive, 1u);
            if (tid == 0) {
                const unsigned int tgt4 = 4u * (unsigned)(tick + 1);
                int gd = 0;
                while (__hip_atomic_load(&arrive, __ATOMIC_RELAXED,
                                         __HIP_MEMORY_SCOPE_WORKGROUP) < tgt4 &&
                       ++gd < (1 << 20)) {
                }
                asm volatile("" ::: "memory");
                __hip_atomic_fetch_add(half ? cntB : cntA, 1u, __ATOMIC_RELAXED,
                                       __HIP_MEMORY_SCOPE_AGENT);
            }
        }

        // ---- (7) poll opposite half's counter; prefetch its h for next tick ----
        if (tick < 1025) {
            const int nhalf = half ^ 1;
            const int nk = half ? (k + 1) : k;
            if (nk > 0) {
                unsigned int* cy = nhalf ? cntB : cntA;
                const unsigned int tgt = 16u * (unsigned)nk;
                unsigned int pv;
                int gd = 0;
                do {
                    asm volatile("global_load_dword %0, %1, off sc0 sc1\n\ts_waitcnt vmcnt(0)"
                                 : "=v"(pv)
                                 : "v"(cy)
                                 : "memory");
                } while (pv < tgt && ++gd < (1 << 17));
            }
            const char* p =
                (const char*)(hbg + (nhalf * 2 + (nk & 1)) * 8192) + tid * 16;
            asm volatile(
                "global_load_dwordx4 %0, %4, off sc0 sc1\n\t"
                "global_load_dwordx4 %1, %5, off sc0 sc1\n\t"
                "global_load_dwordx4 %2, %6, off sc0 sc1\n\t"
                "global_load_dwordx4 %3, %7, off sc0 sc1"
                : "=&v"(st[0]), "=&v"(st[1]), "=&v"(st[2]), "=&v"(st[3])
                : "v"(p), "v"(p + 4096), "v"(p + 8192), "v"(p + 12288)
                : "memory");
        }
    }
}

// ---------------- launch ----------------
extern "C" void kernel_launch(void* const* d_in, const int* in_sizes, int n_in,
                              void* d_out, int out_size, void* d_ws, size_t ws_size,
                              hipStream_t stream) {
    const float* z = (const float*)d_in[0];
    const float* Wih = (const float*)d_in[1];
    const float* Whh = (const float*)d_in[2];
    const float* bih = (const float*)d_in[3];
    const float* bhh = (const float*)d_in[4];
    const float* Wlast = (const float*)d_in[5];
    const float* blast = (const float*)d_in[6];
    float* out = (float*)d_out;

    char* ws = (char*)d_ws;
    unsigned short* Wbig = (unsigned short*)(ws);                // 2,621,440 B
    unsigned short* W0big = (unsigned short*)(ws + 2621440);     // 2,621,440 B
    float* biasEff = (float*)(ws + 5242880);                     // 10,240 B
    float* bias0 = (float*)(ws + 5253120);                       // 10,240 B
    unsigned short* hbuf = (unsigned short*)(ws + 5263360);      // 524,288 B
    unsigned int* counters = (unsigned int*)(ws + 5787648);      // 2,048 B

    k_weff<<<128, 256, 0, stream>>>(Wih, Whh, Wlast, Wbig);
    k_pack<<<512, 256, 0, stream>>>(z, Wih, Whh, bih, bhh, Wlast, blast, Wbig, W0big, biasEff,
                                    bias0, hbuf, counters);
    k_lstm<<<128, 256, 0, stream>>>(Wbig, W0big, biasEff, bias0, hbuf, counters, z, out);
}